// Round 1
// baseline (199.983 us; speedup 1.0000x reference)
//
#include <hip/hip_runtime.h>
#include <stdint.h>

#define WW 48
#define NQ 2304             // 48*48
#define NWT 144             // (bh, qt) tiles of 256 queries
#define SCL 0.51011868f     // 8^-0.5 * log2(e)  (folded so softmax = exp2)
#define SHIFT 17.312340491f // 12 * log2(e)      (fixed-shift softmax)
#define ACCF (NWT * 2304)   // 331776 floats: ACC[wt][9][256]
#define QHF (16 * 48 * 2304)
// ws layout (floats): [0,ACCF) ACC | [ACCF, ACCF+QHF) QH

typedef float v2f __attribute__((ext_vector_type(2)));

__device__ __forceinline__ v2f v2fma(v2f a, v2f b, v2f c) {
    return __builtin_elementwise_fma(a, b, c);   // -> v_pk_fma_f32
}

// ---------------------------------------------------------------------------
// qh_pre: QH[bh][y2][n] = (q_n*SCL) . relh[y2 - y(n) + 47] - SHIFT
// R19: re-gridded 144 -> 576 blocks (4 y2-segments x 144 wt) — R18's 144
// blocks = 0.56 blocks/CU was latency-bound at ~2 waves/CU. bx = seg*144+wt
// keeps bx%8 = wt%8 (144%8==0) so each wt's ACC zeroing + attn atomics stay
// on one XCD. Each seg-block zeroes its quarter of the wt slab.
// ---------------------------------------------------------------------------
__global__ __launch_bounds__(256) void qh_pre(const float* __restrict__ in,
                                              const float* __restrict__ relh,
                                              float* __restrict__ QH,
                                              float* __restrict__ ACC) {
    const int bx = blockIdx.x;
    const int seg = bx / NWT;          // 0..3
    const int wt = bx - seg * NWT;     // 0..143
    float* ab = ACC + (size_t)wt * 2304 + seg * 576;
    for (int i = threadIdx.x; i < 576; i += 256) ab[i] = 0.0f;

    const int bh = wt / 9;
    const int nt = wt - bh * 9;
    const int n = nt * 256 + threadIdx.x;
    const int b = bh >> 3, h = bh & 7;
    const int y = n / WW;

    const float* qp = in + ((size_t)(b * NQ + n) * 192 + h * 8);
    float4 a = *(const float4*)qp, bb = *(const float4*)(qp + 4);
    v2f Q0 = {a.x * SCL, a.y * SCL}, Q1 = {a.z * SCL, a.w * SCL};
    v2f Q2 = {bb.x * SCL, bb.y * SCL}, Q3 = {bb.z * SCL, bb.w * SCL};

    const int y2end = seg * 12 + 12;
    for (int y2 = seg * 12; y2 < y2end; ++y2) {
        const float* rh = relh + (y2 - y + 47) * 8;
        float4 ta = *(const float4*)rh, tb = *(const float4*)(rh + 4);
        v2f s = v2fma(Q0, (v2f){ta.x, ta.y},
                v2fma(Q1, (v2f){ta.z, ta.w},
                v2fma(Q2, (v2f){tb.x, tb.y},
                      Q3 * (v2f){tb.z, tb.w})));
        QH[(size_t)(bh * 48 + y2) * 2304 + n] = s.x + s.y - SHIFT;
    }
}

// ---------------------------------------------------------------------------
// attn: R20 = R15/R18 structure + software-pipelined inner loop.
// Counters at R19 (72.9us): VALUBusy 50%, LDS conflicts 0, HBM 4.5% -> the
// wave stalls ~half its cycles on exposed latency. Two sources:
//  (a) per (row,c): 4 uniform ds_read_b128 of K/V consumed immediately
//      (~100cy exposed per unroll-2 pair, 36 pairs/wave ~= 3600cy), and
//  (b) qh[4][8] batch of 32 global loads at each R-top (~300cy x3).
// Fix: the chunk region is contiguous per R-segment (iteration it reads
// rb + it*16 floats), so fully unroll row x c (all LDS offsets become
// compile-time immediates off one base VGPR) and rotate a depth-1 K/V
// register double-buffer: issue iter i+1's 4 ds_read_b128 before computing
// iter i. qh becomes a per-row rotation qhc[4]/qhn[4] (row r+1's 4
// coalesced QH loads hidden under row r's ~340cy of compute), paying back
// 24 of the 16 VGPRs the K/V buffer costs.
// __launch_bounds__(256,2) is LOAD-BEARING: the only budget that compiles
// this body spill-free (R11: (256,4)->64 VGPR->3.8GB scratch; R17:
// (128,4)->64 VGPR->1.8GB; R7: (192)->48 VGPR spill; R8: (64,1)->128 VGPR
// ok but 7.5% occupancy).
// logit = q.k + q.rel_w[x2-x+47] + q.rel_h[y2-y+47]; p = exp2(logit'-SHIFT)
// ---------------------------------------------------------------------------
__global__ __launch_bounds__(256, 2) void attn_kernel(const float* __restrict__ in,
                                                      const float* __restrict__ relw,
                                                      const float* __restrict__ QH,
                                                      float* __restrict__ ACC) {
    __shared__ float4 lds[1152];       // 18432 B: staging, later 2 merge regions

    const int bx = blockIdx.x;
    const int wt = bx % NWT;           // same-wt blocks share bx%8 -> same XCD
    const int gg = bx / NWT;           // 0..7
    const int bh = wt / 9;
    const int qt = wt - bh * 9;
    const int tid = threadIdx.x;
    const int lane = tid & 63;
    const int wv = tid >> 6;           // 0..3
    const int kc_local = wv >> 1;
    const int rowhalf = wv & 1;
    const int kc = gg * 2 + kc_local;  // 0..15 (3 columns each)
    const int b = bh >> 3, h = bh & 7;

    // ---- stage the block's 2 chunks: 48 rows x 3 cols x [K|V] each ----
    const float4* inp4 = (const float4*)in;
    for (int t = tid; t < 1152; t += 256) {
        const int chunk = t / 576, tt = t - chunk * 576;
        const int key = tt >> 2, p = tt & 3;
        const int row = key / 3, col = key - row * 3;
        const size_t px = (size_t)(b * NQ + row * 48 + (gg * 2 + chunk) * 3 + col) * 48;
        const int c4 = (p < 2) ? (16 + h * 2 + p) : (32 + h * 2 + (p - 2));
        lds[t] = inp4[px + c4];
    }

    // ---- this lane's four queries (packed fp32 pairs) ----
    v2f Q0[4], Q1[4], Q2[4], Q3[4];
    int xq[4];
#pragma unroll
    for (int j = 0; j < 4; ++j) {
        const int n = qt * 256 + j * 64 + lane;
        const int y = n / WW;
        xq[j] = n - y * WW;
        const float* qp = in + ((size_t)(b * NQ + n) * 192 + h * 8);
        float4 a = *(const float4*)qp, bb = *(const float4*)(qp + 4);
        Q0[j] = (v2f){a.x * SCL, a.y * SCL};
        Q1[j] = (v2f){a.z * SCL, a.w * SCL};
        Q2[j] = (v2f){bb.x * SCL, bb.y * SCL};
        Q3[j] = (v2f){bb.z * SCL, bb.w * SCL};
    }

    // ---- qw per (query, chunk column) from global relw ----
    float qw[4][3];
#pragma unroll
    for (int j = 0; j < 4; ++j)
#pragma unroll
        for (int c = 0; c < 3; ++c) {
            const float* rw = relw + (kc * 3 + c - xq[j] + 47) * 8;
            float4 ta = *(const float4*)rw, tb = *(const float4*)(rw + 4);
            v2f s = v2fma(Q0[j], (v2f){ta.x, ta.y},
                    v2fma(Q1[j], (v2f){ta.z, ta.w},
                    v2fma(Q2[j], (v2f){tb.x, tb.y},
                          Q3[j] * (v2f){tb.z, tb.w})));
            qw[j][c] = s.x + s.y;
        }

    __syncthreads();   // staged KV visible to the 2 waves sharing each chunk

    float l[4] = {0, 0, 0, 0};
    v2f A0[4], A1[4], A2[4], A3[4];
#pragma unroll
    for (int j = 0; j < 4; ++j) {
        A0[j] = (v2f){0.f, 0.f}; A1[j] = (v2f){0.f, 0.f};
        A2[j] = (v2f){0.f, 0.f}; A3[j] = (v2f){0.f, 0.f};
    }
    const float* myl = (const float*)(lds + kc_local * 576);
    const float* qhbase = QH + (size_t)bh * 48 * 2304 + qt * 256 + lane;

#pragma unroll 1
    for (int R = 0; R < 3; ++R) {
        const int y2b = rowhalf * 24 + R * 8;
        const float* rb = myl + y2b * 48;   // 24 consecutive 64B [k0,k1,v0,v1] blocks

        // prologue: qh row 0 + K/V iter 0
        float qhc[4], qhn[4];
        {
            const float* qr = qhbase + (size_t)y2b * 2304;
#pragma unroll
            for (int j = 0; j < 4; ++j) qhc[j] = qr[j * 64];
        }
        float4 ck0 = *(const float4*)(rb);
        float4 ck1 = *(const float4*)(rb + 4);
        float4 cv0 = *(const float4*)(rb + 8);
        float4 cv1 = *(const float4*)(rb + 12);

#pragma unroll
        for (int row = 0; row < 8; ++row) {
            // prefetch next row's qh under this row's ~340cy of compute
            {
                const int nr = (row < 7) ? row + 1 : row;
                const float* qrn = qhbase + (size_t)(y2b + nr) * 2304;
#pragma unroll
                for (int j = 0; j < 4; ++j) qhn[j] = qrn[j * 64];
            }
#pragma unroll
            for (int c = 0; c < 3; ++c) {
                const int it = row * 3 + c;
                const int pn = (it < 23) ? it + 1 : it;   // last iter: benign reload
                const float4 nk0 = *(const float4*)(rb + pn * 16);
                const float4 nk1 = *(const float4*)(rb + pn * 16 + 4);
                const float4 nv0 = *(const float4*)(rb + pn * 16 + 8);
                const float4 nv1 = *(const float4*)(rb + pn * 16 + 12);
                const v2f K0 = {ck0.x, ck0.y}, K1 = {ck0.z, ck0.w};
                const v2f K2 = {ck1.x, ck1.y}, K3 = {ck1.z, ck1.w};
                const v2f V0 = {cv0.x, cv0.y}, V1 = {cv0.z, cv0.w};
                const v2f V2 = {cv1.x, cv1.y}, V3 = {cv1.z, cv1.w};
#pragma unroll
                for (int j = 0; j < 4; ++j) {
                    v2f d = v2fma(Q0[j], K0,
                            v2fma(Q1[j], K1,
                            v2fma(Q2[j], K2, Q3[j] * K3)));
                    const float p = __builtin_amdgcn_exp2f(
                        (qhc[j] + qw[j][c]) + (d.x + d.y));
                    l[j] += p;
                    const v2f pp = {p, p};
                    A0[j] = v2fma(pp, V0, A0[j]);
                    A1[j] = v2fma(pp, V1, A1[j]);
                    A2[j] = v2fma(pp, V2, A2[j]);
                    A3[j] = v2fma(pp, V3, A3[j]);
                }
                ck0 = nk0; ck1 = nk1; cv0 = nv0; cv1 = nv1;
            }
#pragma unroll
            for (int j = 0; j < 4; ++j) qhc[j] = qhn[j];
        }
    }

    // ---- two-phase in-block merge (reuse staging LDS: 2 regions) ----
    __syncthreads();   // everyone done reading staged KV
    float* mr = (float*)(lds + kc_local * 576);   // region per wave-pair
    if (rowhalf == 0) {
#pragma unroll
        for (int j = 0; j < 4; ++j) {
            const int q = j * 64 + lane;
            mr[q] = l[j];
            mr[1 * 256 + q] = A0[j].x; mr[2 * 256 + q] = A0[j].y;
            mr[3 * 256 + q] = A1[j].x; mr[4 * 256 + q] = A1[j].y;
            mr[5 * 256 + q] = A2[j].x; mr[6 * 256 + q] = A2[j].y;
            mr[7 * 256 + q] = A3[j].x; mr[8 * 256 + q] = A3[j].y;
        }
    }
    __syncthreads();
    if (rowhalf == 1) {
#pragma unroll
        for (int j = 0; j < 4; ++j) {
            const int q = j * 64 + lane;
            mr[q] += l[j];
            mr[1 * 256 + q] += A0[j].x; mr[2 * 256 + q] += A0[j].y;
            mr[3 * 256 + q] += A1[j].x; mr[4 * 256 + q] += A1[j].y;
            mr[5 * 256 + q] += A2[j].x; mr[6 * 256 + q] += A2[j].y;
            mr[7 * 256 + q] += A3[j].x; mr[8 * 256 + q] += A3[j].y;
        }
    }
    __syncthreads();

    // ---- single atomic layer per block (XCD-local ACC lines) ----
    const float* r0 = (const float*)lds;
    const float* r1 = (const float*)(lds + 576);
    float* ab = ACC + (size_t)wt * 2304;
    for (int idx = tid; idx < 2304; idx += 256)
        atomicAdd(ab + idx, r0[idx] + r1[idx]);
}

// ---------------------------------------------------------------------------
// normalize: read ACC, divide by l, write out[b][n][h*8+j]
// R19: 576 blocks x 64 threads (was 144 x 256) for 4x scheduling units.
// ---------------------------------------------------------------------------
__global__ __launch_bounds__(64) void norm_kernel(const float* __restrict__ ACC,
                                                  float* __restrict__ out) {
    const int bxx = blockIdx.x;
    const int wt = bxx >> 2;
    const int q = (bxx & 3) * 64 + threadIdx.x;
    const float* ab = ACC + (size_t)wt * 2304;
    const float inv = 1.0f / ab[q];
    float s[8];
#pragma unroll
    for (int e = 0; e < 8; ++e) s[e] = ab[(1 + e) * 256 + q] * inv;
    const int bh = wt / 9;
    const int qtl = wt - bh * 9;
    const int n = qtl * 256 + q;
    const int b = bh >> 3, h = bh & 7;
    float* op = out + ((size_t)(b * NQ + n) * 64 + h * 8);
    ((float4*)op)[0] = make_float4(s[0], s[1], s[2], s[3]);
    ((float4*)op)[1] = make_float4(s[4], s[5], s[6], s[7]);
}

extern "C" void kernel_launch(void* const* d_in, const int* in_sizes, int n_in,
                              void* d_out, int out_size, void* d_ws, size_t ws_size,
                              hipStream_t stream) {
    const float* in   = (const float*)d_in[0];
    const float* relw = (const float*)d_in[1];
    const float* relh = (const float*)d_in[2];
    float* ACC = (float*)d_ws;                 // 1.33 MB
    float* QH  = (float*)d_ws + ACCF;          // 7.08 MB
    float* out = (float*)d_out;

    qh_pre<<<4 * NWT, 256, 0, stream>>>(in, relh, QH, ACC);
    attn_kernel<<<8 * NWT, 256, 0, stream>>>(in, relw, QH, ACC);
    norm_kernel<<<4 * NWT, 64, 0, stream>>>(ACC, out);
}

// Round 2
// 127.991 us; speedup vs baseline: 1.5625x; 1.5625x over previous
//
#include <hip/hip_runtime.h>
#include <stdint.h>

#define WW 48
#define NQ 2304             // 48*48
#define NWT 144             // (bh, qt) tiles of 256 queries
#define SCL 0.51011868f     // 8^-0.5 * log2(e)  (folded so softmax = exp2)
#define SHIFT 17.312340491f // 12 * log2(e)      (fixed-shift softmax)
#define ACCF (NWT * 2304)   // 331776 floats: ACC[wt][9][256]
#define QHF (16 * 48 * 2304)
// ws layout (floats): [0,ACCF) ACC | [ACCF, ACCF+QHF) QH

typedef float v2f __attribute__((ext_vector_type(2)));

__device__ __forceinline__ v2f v2fma(v2f a, v2f b, v2f c) {
    return __builtin_elementwise_fma(a, b, c);   // -> v_pk_fma_f32
}

// ---------------------------------------------------------------------------
// qh_pre: QH[bh][y2][n] = (q_n*SCL) . relh[y2 - y(n) + 47] - SHIFT
// R19: re-gridded 144 -> 576 blocks (4 y2-segments x 144 wt). bx = seg*144+wt
// keeps bx%8 = wt%8 (144%8==0) so each wt's ACC zeroing + attn atomics stay
// on one XCD. Each seg-block zeroes its quarter of the wt slab.
// ---------------------------------------------------------------------------
__global__ __launch_bounds__(256) void qh_pre(const float* __restrict__ in,
                                              const float* __restrict__ relh,
                                              float* __restrict__ QH,
                                              float* __restrict__ ACC) {
    const int bx = blockIdx.x;
    const int seg = bx / NWT;          // 0..3
    const int wt = bx - seg * NWT;     // 0..143
    float* ab = ACC + (size_t)wt * 2304 + seg * 576;
    for (int i = threadIdx.x; i < 576; i += 256) ab[i] = 0.0f;

    const int bh = wt / 9;
    const int nt = wt - bh * 9;
    const int n = nt * 256 + threadIdx.x;
    const int b = bh >> 3, h = bh & 7;
    const int y = n / WW;

    const float* qp = in + ((size_t)(b * NQ + n) * 192 + h * 8);
    float4 a = *(const float4*)qp, bb = *(const float4*)(qp + 4);
    v2f Q0 = {a.x * SCL, a.y * SCL}, Q1 = {a.z * SCL, a.w * SCL};
    v2f Q2 = {bb.x * SCL, bb.y * SCL}, Q3 = {bb.z * SCL, bb.w * SCL};

    const int y2end = seg * 12 + 12;
    for (int y2 = seg * 12; y2 < y2end; ++y2) {
        const float* rh = relh + (y2 - y + 47) * 8;
        float4 ta = *(const float4*)rh, tb = *(const float4*)(rh + 4);
        v2f s = v2fma(Q0, (v2f){ta.x, ta.y},
                v2fma(Q1, (v2f){ta.z, ta.w},
                v2fma(Q2, (v2f){tb.x, tb.y},
                      Q3 * (v2f){tb.z, tb.w})));
        QH[(size_t)(bh * 48 + y2) * 2304 + n] = s.x + s.y - SHIFT;
    }
}

// ---------------------------------------------------------------------------
// attn: R21 = exact R15/R18/R19 inner-loop body (the only spill-free form:
// R20's register double-buffer pipelining spilled — VGPR 96->128 + 250MB of
// scratch traffic, VALUBusy 0.7%. DO NOT re-add in-register pipelining at
// this budget). R21 lever: occupancy. R19 ran VALUBusy 50% / Occ 17%
// (~1.4 blocks/CU) with 1152 blocks each staging 2 chunks and 24 rows/wave.
// Now: 2304 blocks (gg = 0..15), each stages ONE 3-column chunk (9.2KB) and
// splits the 48 rows 4-way across its waves (12 rows/wave). Halves per-wave
// critical path, doubles schedulable blocks, and shrinks live state
// (qh[4][8] -> qh[4][4]). Atomic layer doubles (16 blocks/wt) — still
// XCD-local since bx%8 = wt%8 (144%8==0).
// __launch_bounds__(256,2) is LOAD-BEARING: the only budget that compiles
// this body spill-free (R11: (256,4)->64 VGPR->3.8GB scratch; R17:
// (128,4)->64 VGPR->1.8GB; R7: (192)->48 VGPR spill; R8: (64,1)->128 VGPR
// ok but 7.5% occupancy; R20: pipelined body -> 128 VGPR + scratch).
// logit = q.k + q.rel_w[x2-x+47] + q.rel_h[y2-y+47]; p = exp2(logit'-SHIFT)
// ---------------------------------------------------------------------------
__global__ __launch_bounds__(256, 2) void attn_kernel(const float* __restrict__ in,
                                                      const float* __restrict__ relw,
                                                      const float* __restrict__ QH,
                                                      float* __restrict__ ACC) {
    __shared__ float4 lds[1152];       // 18432 B: 9.2KB staging, later 2 merge regions

    const int bx = blockIdx.x;
    const int wt = bx % NWT;           // same-wt blocks share bx%8 -> same XCD
    const int gg = bx / NWT;           // 0..15 (one 3-column chunk each)
    const int bh = wt / 9;
    const int qt = wt - bh * 9;
    const int tid = threadIdx.x;
    const int lane = tid & 63;
    const int wv = tid >> 6;           // 0..3 = row quarter
    const int kc = gg;                 // chunk column group (3 columns)
    const int b = bh >> 3, h = bh & 7;

    // ---- stage this block's chunk: 48 rows x 3 cols x [K|V] ----
    const float4* inp4 = (const float4*)in;
    for (int t = tid; t < 576; t += 256) {
        const int key = t >> 2, p = t & 3;
        const int row = key / 3, col = key - row * 3;
        const size_t px = (size_t)(b * NQ + row * 48 + kc * 3 + col) * 48;
        const int c4 = (p < 2) ? (16 + h * 2 + p) : (32 + h * 2 + (p - 2));
        lds[t] = inp4[px + c4];
    }

    // ---- this lane's four queries (packed fp32 pairs) ----
    v2f Q0[4], Q1[4], Q2[4], Q3[4];
    int xq[4];
#pragma unroll
    for (int j = 0; j < 4; ++j) {
        const int n = qt * 256 + j * 64 + lane;
        const int y = n / WW;
        xq[j] = n - y * WW;
        const float* qp = in + ((size_t)(b * NQ + n) * 192 + h * 8);
        float4 a = *(const float4*)qp, bb = *(const float4*)(qp + 4);
        Q0[j] = (v2f){a.x * SCL, a.y * SCL};
        Q1[j] = (v2f){a.z * SCL, a.w * SCL};
        Q2[j] = (v2f){bb.x * SCL, bb.y * SCL};
        Q3[j] = (v2f){bb.z * SCL, bb.w * SCL};
    }

    // ---- qw per (query, chunk column) from global relw ----
    float qw[4][3];
#pragma unroll
    for (int j = 0; j < 4; ++j)
#pragma unroll
        for (int c = 0; c < 3; ++c) {
            const float* rw = relw + (kc * 3 + c - xq[j] + 47) * 8;
            float4 ta = *(const float4*)rw, tb = *(const float4*)(rw + 4);
            v2f s = v2fma(Q0[j], (v2f){ta.x, ta.y},
                    v2fma(Q1[j], (v2f){ta.z, ta.w},
                    v2fma(Q2[j], (v2f){tb.x, tb.y},
                          Q3[j] * (v2f){tb.z, tb.w})));
            qw[j][c] = s.x + s.y;
        }

    __syncthreads();   // staged KV visible to all 4 waves

    float l[4] = {0, 0, 0, 0};
    v2f A0[4], A1[4], A2[4], A3[4];
#pragma unroll
    for (int j = 0; j < 4; ++j) {
        A0[j] = (v2f){0.f, 0.f}; A1[j] = (v2f){0.f, 0.f};
        A2[j] = (v2f){0.f, 0.f}; A3[j] = (v2f){0.f, 0.f};
    }
    const float* myl = (const float*)lds;
    const float* qhbase = QH + (size_t)bh * 48 * 2304 + qt * 256 + lane;

#pragma unroll 1
    for (int R = 0; R < 3; ++R) {
        // ---- qh for this round's 4 rows: coalesced dword loads ----
        float qh[4][4];
#pragma unroll
        for (int row = 0; row < 4; ++row) {
            const int y2 = wv * 12 + R * 4 + row;
            const float* qr = qhbase + (size_t)y2 * 2304;
#pragma unroll
            for (int j = 0; j < 4; ++j) qh[j][row] = qr[j * 64];
        }

#pragma unroll 2
        for (int row = 0; row < 4; ++row) {
            const int y2 = wv * 12 + R * 4 + row;
#pragma unroll
            for (int c = 0; c < 3; ++c) {
                const int base = (y2 * 3 + c) * 16;     // wave-uniform
                const float4 k0 = *(const float4*)(myl + base);
                const float4 k1 = *(const float4*)(myl + base + 4);
                const float4 v0 = *(const float4*)(myl + base + 8);
                const float4 v1 = *(const float4*)(myl + base + 12);
                const v2f K0 = {k0.x, k0.y}, K1 = {k0.z, k0.w};
                const v2f K2 = {k1.x, k1.y}, K3 = {k1.z, k1.w};
                const v2f V0 = {v0.x, v0.y}, V1 = {v0.z, v0.w};
                const v2f V2 = {v1.x, v1.y}, V3 = {v1.z, v1.w};
#pragma unroll
                for (int j = 0; j < 4; ++j) {
                    v2f d = v2fma(Q0[j], K0,
                            v2fma(Q1[j], K1,
                            v2fma(Q2[j], K2, Q3[j] * K3)));
                    const float p = __builtin_amdgcn_exp2f(
                        (qh[j][row] + qw[j][c]) + (d.x + d.y));
                    l[j] += p;
                    const v2f pp = {p, p};
                    A0[j] = v2fma(pp, V0, A0[j]);
                    A1[j] = v2fma(pp, V1, A1[j]);
                    A2[j] = v2fma(pp, V2, A2[j]);
                    A3[j] = v2fma(pp, V3, A3[j]);
                }
            }
        }
    }

    // ---- two-phase in-block merge (reuse LDS: 2 regions of 2304 floats) ----
    __syncthreads();   // everyone done reading staged KV
    float* mr = (float*)(lds + (wv >> 1) * 576);   // region per wave-pair
    if ((wv & 1) == 0) {
#pragma unroll
        for (int j = 0; j < 4; ++j) {
            const int q = j * 64 + lane;
            mr[q] = l[j];
            mr[1 * 256 + q] = A0[j].x; mr[2 * 256 + q] = A0[j].y;
            mr[3 * 256 + q] = A1[j].x; mr[4 * 256 + q] = A1[j].y;
            mr[5 * 256 + q] = A2[j].x; mr[6 * 256 + q] = A2[j].y;
            mr[7 * 256 + q] = A3[j].x; mr[8 * 256 + q] = A3[j].y;
        }
    }
    __syncthreads();
    if ((wv & 1) == 1) {
#pragma unroll
        for (int j = 0; j < 4; ++j) {
            const int q = j * 64 + lane;
            mr[q] += l[j];
            mr[1 * 256 + q] += A0[j].x; mr[2 * 256 + q] += A0[j].y;
            mr[3 * 256 + q] += A1[j].x; mr[4 * 256 + q] += A1[j].y;
            mr[5 * 256 + q] += A2[j].x; mr[6 * 256 + q] += A2[j].y;
            mr[7 * 256 + q] += A3[j].x; mr[8 * 256 + q] += A3[j].y;
        }
    }
    __syncthreads();

    // ---- single atomic layer per block (XCD-local ACC lines) ----
    const float* r0 = (const float*)lds;
    const float* r1 = (const float*)(lds + 576);
    float* ab = ACC + (size_t)wt * 2304;
    for (int idx = tid; idx < 2304; idx += 256)
        atomicAdd(ab + idx, r0[idx] + r1[idx]);
}

// ---------------------------------------------------------------------------
// normalize: read ACC, divide by l, write out[b][n][h*8+j]
// R19: 576 blocks x 64 threads (was 144 x 256) for 4x scheduling units.
// ---------------------------------------------------------------------------
__global__ __launch_bounds__(64) void norm_kernel(const float* __restrict__ ACC,
                                                  float* __restrict__ out) {
    const int bxx = blockIdx.x;
    const int wt = bxx >> 2;
    const int q = (bxx & 3) * 64 + threadIdx.x;
    const float* ab = ACC + (size_t)wt * 2304;
    const float inv = 1.0f / ab[q];
    float s[8];
#pragma unroll
    for (int e = 0; e < 8; ++e) s[e] = ab[(1 + e) * 256 + q] * inv;
    const int bh = wt / 9;
    const int qtl = wt - bh * 9;
    const int n = qtl * 256 + q;
    const int b = bh >> 3, h = bh & 7;
    float* op = out + ((size_t)(b * NQ + n) * 64 + h * 8);
    ((float4*)op)[0] = make_float4(s[0], s[1], s[2], s[3]);
    ((float4*)op)[1] = make_float4(s[4], s[5], s[6], s[7]);
}

extern "C" void kernel_launch(void* const* d_in, const int* in_sizes, int n_in,
                              void* d_out, int out_size, void* d_ws, size_t ws_size,
                              hipStream_t stream) {
    const float* in   = (const float*)d_in[0];
    const float* relw = (const float*)d_in[1];
    const float* relh = (const float*)d_in[2];
    float* ACC = (float*)d_ws;                 // 1.33 MB
    float* QH  = (float*)d_ws + ACCF;          // 7.08 MB
    float* out = (float*)d_out;

    qh_pre<<<4 * NWT, 256, 0, stream>>>(in, relh, QH, ACC);
    attn_kernel<<<16 * NWT, 256, 0, stream>>>(in, relw, QH, ACC);
    norm_kernel<<<4 * NWT, 64, 0, stream>>>(ACC, out);
}

// Round 3
// 120.681 us; speedup vs baseline: 1.6571x; 1.0606x over previous
//
#include <hip/hip_runtime.h>
#include <stdint.h>

#define WW 48
#define NQ 2304             // 48*48
#define NWT 144             // (bh, qt) tiles of 256 queries
#define SCL 0.51011868f     // 8^-0.5 * log2(e)  (folded so softmax = exp2)
#define SHIFT 17.312340491f // 12 * log2(e)      (fixed-shift softmax)
#define ACCF (NWT * 2304)   // 331776 floats: ACC[wt][9][256]
// ws layout (floats): [0,ACCF) ACC   (QH stage eliminated in R22)

typedef float v2f __attribute__((ext_vector_type(2)));

__device__ __forceinline__ v2f v2fma(v2f a, v2f b, v2f c) {
    return __builtin_elementwise_fma(a, b, c);   // -> v_pk_fma_f32
}

// ---------------------------------------------------------------------------
// attn: R22 = R21 grid/body with the QH stage eliminated.
// R21 counters (77.9us attn, 128us total): VALUBusy pinned ~50% across
// occupancy 17->19% and across per-wave-work halving => adding waves doesn't
// fill issue slots; and total - attn = ~50us of qh_pre + norm + gaps.
// R22: delete qh_pre. qh[j][row] = Q[j].relh[y2-y_j+47] is computed inline
// from relh staged in LDS (3KB, 190 float4): per (j,row) 2 near-broadcast
// ds_reads (lanes span 2 y values -> 2-way, free) + 4 pk_fma + 1 add.
// Replaces 48 global QH loads/wave (L2 latency in dependency path) and a
// whole kernel + launch gap + 7MB QH write. SHIFT folds into qw. ACC
// zeroing -> hipMemsetAsync (graph-capture-safe).
// Inner (row,c) body is byte-identical to the proven spill-free form.
// __launch_bounds__(256,2) is LOAD-BEARING: the only budget that compiles
// this body spill-free (R11: (256,4)->64 VGPR->3.8GB scratch; R17:
// (128,4)->64 VGPR->1.8GB; R7: (192)->48 VGPR spill; R8: (64,1)->128 VGPR
// ok but 7.5% occupancy; R20: in-register pipelining -> 128 VGPR + 250MB
// scratch traffic. DO NOT re-add register double-buffering).
// logit = q.k + q.rel_w[x2-x+47] + q.rel_h[y2-y+47]; p = exp2(logit-SHIFT)
// ---------------------------------------------------------------------------
__global__ __launch_bounds__(256, 2) void attn_kernel(const float* __restrict__ in,
                                                      const float* __restrict__ relw,
                                                      const float* __restrict__ relh,
                                                      float* __restrict__ ACC) {
    __shared__ float4 lds[1342];       // 21472 B: [0,576) KV chunk, later 2 merge
                                       // regions [0,1152); [1152,1342) relh

    const int bx = blockIdx.x;
    const int wt = bx % NWT;           // same-wt blocks share bx%8 -> same XCD
    const int gg = bx / NWT;           // 0..15 (one 3-column chunk each)
    const int bh = wt / 9;
    const int qt = wt - bh * 9;
    const int tid = threadIdx.x;
    const int lane = tid & 63;
    const int wv = tid >> 6;           // 0..3 = row quarter
    const int kc = gg;                 // chunk column group (3 columns)
    const int b = bh >> 3, h = bh & 7;

    // ---- stage this block's chunk: 48 rows x 3 cols x [K|V] ----
    const float4* inp4 = (const float4*)in;
    for (int t = tid; t < 576; t += 256) {
        const int key = t >> 2, p = t & 3;
        const int row = key / 3, col = key - row * 3;
        const size_t px = (size_t)(b * NQ + row * 48 + kc * 3 + col) * 48;
        const int c4 = (p < 2) ? (16 + h * 2 + p) : (32 + h * 2 + (p - 2));
        lds[t] = inp4[px + c4];
    }
    // ---- stage relh: 95 rows x 8 floats = 190 float4 ----
    for (int t = tid; t < 190; t += 256) lds[1152 + t] = ((const float4*)relh)[t];

    // ---- this lane's four queries (packed fp32 pairs) ----
    v2f Q0[4], Q1[4], Q2[4], Q3[4];
    int xq[4], ro[4];
#pragma unroll
    for (int j = 0; j < 4; ++j) {
        const int n = qt * 256 + j * 64 + lane;
        const int y = n / WW;
        xq[j] = n - y * WW;
        ro[j] = (47 - y) * 8;          // relh row offset (floats), + y2*8 in loop
        const float* qp = in + ((size_t)(b * NQ + n) * 192 + h * 8);
        float4 a = *(const float4*)qp, bb = *(const float4*)(qp + 4);
        Q0[j] = (v2f){a.x * SCL, a.y * SCL};
        Q1[j] = (v2f){a.z * SCL, a.w * SCL};
        Q2[j] = (v2f){bb.x * SCL, bb.y * SCL};
        Q3[j] = (v2f){bb.z * SCL, bb.w * SCL};
    }

    // ---- qw per (query, chunk column) from global relw; SHIFT folded in ----
    float qw[4][3];
#pragma unroll
    for (int j = 0; j < 4; ++j)
#pragma unroll
        for (int c = 0; c < 3; ++c) {
            const float* rw = relw + (kc * 3 + c - xq[j] + 47) * 8;
            float4 ta = *(const float4*)rw, tb = *(const float4*)(rw + 4);
            v2f s = v2fma(Q0[j], (v2f){ta.x, ta.y},
                    v2fma(Q1[j], (v2f){ta.z, ta.w},
                    v2fma(Q2[j], (v2f){tb.x, tb.y},
                          Q3[j] * (v2f){tb.z, tb.w})));
            qw[j][c] = s.x + s.y - SHIFT;
        }

    __syncthreads();   // staged KV + relh visible to all 4 waves

    float l[4] = {0, 0, 0, 0};
    v2f A0[4], A1[4], A2[4], A3[4];
#pragma unroll
    for (int j = 0; j < 4; ++j) {
        A0[j] = (v2f){0.f, 0.f}; A1[j] = (v2f){0.f, 0.f};
        A2[j] = (v2f){0.f, 0.f}; A3[j] = (v2f){0.f, 0.f};
    }
    const float* myl = (const float*)lds;
    const float* relh_lds = (const float*)(lds + 1152);

#pragma unroll 1
    for (int R = 0; R < 3; ++R) {
#pragma unroll 2
        for (int row = 0; row < 4; ++row) {
            const int y2 = wv * 12 + R * 4 + row;
            // ---- qh inline: 2 near-broadcast LDS reads + 4 pk_fma per j ----
            float qhv[4];
#pragma unroll
            for (int j = 0; j < 4; ++j) {
                const float* rp = relh_lds + ro[j] + y2 * 8;
                const float4 ra = *(const float4*)rp;
                const float4 rb = *(const float4*)(rp + 4);
                v2f s = v2fma(Q0[j], (v2f){ra.x, ra.y},
                        v2fma(Q1[j], (v2f){ra.z, ra.w},
                        v2fma(Q2[j], (v2f){rb.x, rb.y},
                              Q3[j] * (v2f){rb.z, rb.w})));
                qhv[j] = s.x + s.y;
            }
#pragma unroll
            for (int c = 0; c < 3; ++c) {
                const int base = (y2 * 3 + c) * 16;     // wave-uniform
                const float4 k0 = *(const float4*)(myl + base);
                const float4 k1 = *(const float4*)(myl + base + 4);
                const float4 v0 = *(const float4*)(myl + base + 8);
                const float4 v1 = *(const float4*)(myl + base + 12);
                const v2f K0 = {k0.x, k0.y}, K1 = {k0.z, k0.w};
                const v2f K2 = {k1.x, k1.y}, K3 = {k1.z, k1.w};
                const v2f V0 = {v0.x, v0.y}, V1 = {v0.z, v0.w};
                const v2f V2 = {v1.x, v1.y}, V3 = {v1.z, v1.w};
#pragma unroll
                for (int j = 0; j < 4; ++j) {
                    v2f d = v2fma(Q0[j], K0,
                            v2fma(Q1[j], K1,
                            v2fma(Q2[j], K2, Q3[j] * K3)));
                    const float p = __builtin_amdgcn_exp2f(
                        (qhv[j] + qw[j][c]) + (d.x + d.y));
                    l[j] += p;
                    const v2f pp = {p, p};
                    A0[j] = v2fma(pp, V0, A0[j]);
                    A1[j] = v2fma(pp, V1, A1[j]);
                    A2[j] = v2fma(pp, V2, A2[j]);
                    A3[j] = v2fma(pp, V3, A3[j]);
                }
            }
        }
    }

    // ---- two-phase in-block merge (reuse LDS: 2 regions of 2304 floats) ----
    __syncthreads();   // everyone done reading staged KV/relh
    float* mr = (float*)(lds + (wv >> 1) * 576);   // region per wave-pair
    if ((wv & 1) == 0) {
#pragma unroll
        for (int j = 0; j < 4; ++j) {
            const int q = j * 64 + lane;
            mr[q] = l[j];
            mr[1 * 256 + q] = A0[j].x; mr[2 * 256 + q] = A0[j].y;
            mr[3 * 256 + q] = A1[j].x; mr[4 * 256 + q] = A1[j].y;
            mr[5 * 256 + q] = A2[j].x; mr[6 * 256 + q] = A2[j].y;
            mr[7 * 256 + q] = A3[j].x; mr[8 * 256 + q] = A3[j].y;
        }
    }
    __syncthreads();
    if ((wv & 1) == 1) {
#pragma unroll
        for (int j = 0; j < 4; ++j) {
            const int q = j * 64 + lane;
            mr[q] += l[j];
            mr[1 * 256 + q] += A0[j].x; mr[2 * 256 + q] += A0[j].y;
            mr[3 * 256 + q] += A1[j].x; mr[4 * 256 + q] += A1[j].y;
            mr[5 * 256 + q] += A2[j].x; mr[6 * 256 + q] += A2[j].y;
            mr[7 * 256 + q] += A3[j].x; mr[8 * 256 + q] += A3[j].y;
        }
    }
    __syncthreads();

    // ---- single atomic layer per block (XCD-local ACC lines) ----
    const float* r0 = (const float*)lds;
    const float* r1 = (const float*)(lds + 576);
    float* ab = ACC + (size_t)wt * 2304;
    for (int idx = tid; idx < 2304; idx += 256)
        atomicAdd(ab + idx, r0[idx] + r1[idx]);
}

// ---------------------------------------------------------------------------
// normalize: read ACC, divide by l, write out[b][n][h*8+j]
// R19: 576 blocks x 64 threads for 4x scheduling units.
// ---------------------------------------------------------------------------
__global__ __launch_bounds__(64) void norm_kernel(const float* __restrict__ ACC,
                                                  float* __restrict__ out) {
    const int bxx = blockIdx.x;
    const int wt = bxx >> 2;
    const int q = (bxx & 3) * 64 + threadIdx.x;
    const float* ab = ACC + (size_t)wt * 2304;
    const float inv = 1.0f / ab[q];
    float s[8];
#pragma unroll
    for (int e = 0; e < 8; ++e) s[e] = ab[(1 + e) * 256 + q] * inv;
    const int bh = wt / 9;
    const int qtl = wt - bh * 9;
    const int n = qtl * 256 + q;
    const int b = bh >> 3, h = bh & 7;
    float* op = out + ((size_t)(b * NQ + n) * 64 + h * 8);
    ((float4*)op)[0] = make_float4(s[0], s[1], s[2], s[3]);
    ((float4*)op)[1] = make_float4(s[4], s[5], s[6], s[7]);
}

extern "C" void kernel_launch(void* const* d_in, const int* in_sizes, int n_in,
                              void* d_out, int out_size, void* d_ws, size_t ws_size,
                              hipStream_t stream) {
    const float* in   = (const float*)d_in[0];
    const float* relw = (const float*)d_in[1];
    const float* relh = (const float*)d_in[2];
    float* ACC = (float*)d_ws;                 // 1.33 MB
    float* out = (float*)d_out;

    hipMemsetAsync(ACC, 0, ACCF * sizeof(float), stream);
    attn_kernel<<<16 * NWT, 256, 0, stream>>>(in, relw, relh, ACC);
    norm_kernel<<<4 * NWT, 64, 0, stream>>>(ACC, out);
}

// Round 4
// 118.508 us; speedup vs baseline: 1.6875x; 1.0183x over previous
//
#include <hip/hip_runtime.h>
#include <stdint.h>

#define WW 48
#define NQ 2304             // 48*48
#define NWT 144             // (bh, qt) tiles of 256 queries
#define SCL 0.51011868f     // 8^-0.5 * log2(e)  (folded so softmax = exp2)
#define SHIFT 17.312340491f // 12 * log2(e)      (fixed-shift softmax)
#define ACCF (NWT * 2304)   // 331776 floats: ACC[wt][9][256]
// ws layout (floats): [0,ACCF) ACC   (QH stage eliminated in R22)

typedef float v2f __attribute__((ext_vector_type(2)));

__device__ __forceinline__ v2f v2fma(v2f a, v2f b, v2f c) {
    return __builtin_elementwise_fma(a, b, c);   // -> v_pk_fma_f32
}

// ---------------------------------------------------------------------------
// attn: R23 = R22 with K/V moved from LDS staging to wave-uniform direct
// global reads (target: s_load scalarization).
// R22 counters (71.4us attn): VALUBusy 65% CU-level ~= 20-25% per-SIMD issue
// (pure VALU floor ~14us) => stall-bound. Dominant pipe: LDS — 240 ds ops
// per wave x ~12cyc x 9216 waves / 256 CU ~= 43us of LDS-unit occupancy in
// the dependency path. All K/V reads are wave-uniform 32B chunks ->
// belong in SGPRs via s_load (scalar pipe, free), not broadcast ds_read.
// __builtin_amdgcn_readfirstlane(tid>>6) makes the wave-id provably uniform
// so the whole K/V address chain is uniform; all pointers __restrict__ so
// the no-clobber condition for s_load promotion holds. KV staging loop
// deleted; LDS keeps relh (3KB) + merge regions. Main-loop LDS ops/wave:
// 240 -> 96 (relh only). Diagnostic: SGPR_Count ~96 -> ~104 iff promotion
// fired; if it stays, next lever is inline s_load asm.
// __launch_bounds__(256,2) is LOAD-BEARING: the only budget that compiles
// this body spill-free (R11: (256,4)->64 VGPR->3.8GB scratch; R17:
// (128,4)->64 VGPR->1.8GB; R7: (192)->48 VGPR spill; R8: (64,1)->128 VGPR
// ok but 7.5% occupancy; R20: in-register pipelining -> 128 VGPR + 250MB
// scratch traffic. DO NOT re-add register double-buffering).
// logit = q.k + q.rel_w[x2-x+47] + q.rel_h[y2-y+47]; p = exp2(logit-SHIFT)
// ---------------------------------------------------------------------------
__global__ __launch_bounds__(256, 2) void attn_kernel(const float* __restrict__ in,
                                                      const float* __restrict__ relw,
                                                      const float* __restrict__ relh,
                                                      float* __restrict__ ACC) {
    __shared__ float4 lds[1152];       // 18432 B: [0,190) relh during loop;
                                       // [0,1152) merge regions after loop

    const int bx = blockIdx.x;
    const int wt = bx % NWT;           // same-wt blocks share bx%8 -> same XCD
    const int gg = bx / NWT;           // 0..15 (one 3-column chunk each)
    const int bh = wt / 9;
    const int qt = wt - bh * 9;
    const int tid = threadIdx.x;
    const int lane = tid & 63;
    const int wv = tid >> 6;           // 0..3 = row quarter (divergent form)
    const int wvu = __builtin_amdgcn_readfirstlane(wv);  // provably uniform
    const int kc = gg;                 // chunk column group (3 columns)
    const int b = bh >> 3, h = bh & 7;

    // ---- stage relh: 95 rows x 8 floats = 190 float4 ----
    for (int t = tid; t < 190; t += 256) lds[t] = ((const float4*)relh)[t];

    // ---- this lane's four queries (packed fp32 pairs) ----
    v2f Q0[4], Q1[4], Q2[4], Q3[4];
    int xq[4], ro[4];
#pragma unroll
    for (int j = 0; j < 4; ++j) {
        const int n = qt * 256 + j * 64 + lane;
        const int y = n / WW;
        xq[j] = n - y * WW;
        ro[j] = (47 - y) * 8;          // relh row offset (floats), + y2*8 in loop
        const float* qp = in + ((size_t)(b * NQ + n) * 192 + h * 8);
        float4 a = *(const float4*)qp, bb = *(const float4*)(qp + 4);
        Q0[j] = (v2f){a.x * SCL, a.y * SCL};
        Q1[j] = (v2f){a.z * SCL, a.w * SCL};
        Q2[j] = (v2f){bb.x * SCL, bb.y * SCL};
        Q3[j] = (v2f){bb.z * SCL, bb.w * SCL};
    }

    // ---- qw per (query, chunk column) from global relw; SHIFT folded in ----
    float qw[4][3];
#pragma unroll
    for (int j = 0; j < 4; ++j)
#pragma unroll
        for (int c = 0; c < 3; ++c) {
            const float* rw = relw + (kc * 3 + c - xq[j] + 47) * 8;
            float4 ta = *(const float4*)rw, tb = *(const float4*)(rw + 4);
            v2f s = v2fma(Q0[j], (v2f){ta.x, ta.y},
                    v2fma(Q1[j], (v2f){ta.z, ta.w},
                    v2fma(Q2[j], (v2f){tb.x, tb.y},
                          Q3[j] * (v2f){tb.z, tb.w})));
            qw[j][c] = s.x + s.y - SHIFT;
        }

    __syncthreads();   // staged relh visible to all 4 waves

    float l[4] = {0, 0, 0, 0};
    v2f A0[4], A1[4], A2[4], A3[4];
#pragma unroll
    for (int j = 0; j < 4; ++j) {
        A0[j] = (v2f){0.f, 0.f}; A1[j] = (v2f){0.f, 0.f};
        A2[j] = (v2f){0.f, 0.f}; A3[j] = (v2f){0.f, 0.f};
    }
    const float* relh_lds = (const float*)lds;

#pragma unroll 1
    for (int R = 0; R < 3; ++R) {
#pragma unroll 2
        for (int row = 0; row < 4; ++row) {
            const int y2 = wvu * 12 + R * 4 + row;      // uniform chain
            // ---- qh inline: 2 near-broadcast LDS reads + 4 pk_fma per j ----
            float qhv[4];
#pragma unroll
            for (int j = 0; j < 4; ++j) {
                const float* rp = relh_lds + ro[j] + y2 * 8;
                const float4 ra = *(const float4*)rp;
                const float4 rb = *(const float4*)(rp + 4);
                v2f s = v2fma(Q0[j], (v2f){ra.x, ra.y},
                        v2fma(Q1[j], (v2f){ra.z, ra.w},
                        v2fma(Q2[j], (v2f){rb.x, rb.y},
                              Q3[j] * (v2f){rb.z, rb.w})));
                qhv[j] = s.x + s.y;
            }
            // ---- K/V: wave-uniform 32B chunks straight from global ----
            const float* kvrow = in + (size_t)(b * NQ + y2 * 48 + kc * 3) * 192
                                    + h * 8;
#pragma unroll
            for (int c = 0; c < 3; ++c) {
                const float* kvb = kvrow + c * 192;
                const float4 k0 = *(const float4*)(kvb + 64);
                const float4 k1 = *(const float4*)(kvb + 68);
                const float4 v0 = *(const float4*)(kvb + 128);
                const float4 v1 = *(const float4*)(kvb + 132);
                const v2f K0 = {k0.x, k0.y}, K1 = {k0.z, k0.w};
                const v2f K2 = {k1.x, k1.y}, K3 = {k1.z, k1.w};
                const v2f V0 = {v0.x, v0.y}, V1 = {v0.z, v0.w};
                const v2f V2 = {v1.x, v1.y}, V3 = {v1.z, v1.w};
#pragma unroll
                for (int j = 0; j < 4; ++j) {
                    v2f d = v2fma(Q0[j], K0,
                            v2fma(Q1[j], K1,
                            v2fma(Q2[j], K2, Q3[j] * K3)));
                    const float p = __builtin_amdgcn_exp2f(
                        (qhv[j] + qw[j][c]) + (d.x + d.y));
                    l[j] += p;
                    const v2f pp = {p, p};
                    A0[j] = v2fma(pp, V0, A0[j]);
                    A1[j] = v2fma(pp, V1, A1[j]);
                    A2[j] = v2fma(pp, V2, A2[j]);
                    A3[j] = v2fma(pp, V3, A3[j]);
                }
            }
        }
    }

    // ---- two-phase in-block merge (LDS: 2 regions of 2304 floats) ----
    __syncthreads();   // all waves done reading relh; safe to overwrite
    float* mr = (float*)(lds + (wv >> 1) * 576);   // region per wave-pair
    if ((wv & 1) == 0) {
#pragma unroll
        for (int j = 0; j < 4; ++j) {
            const int q = j * 64 + lane;
            mr[q] = l[j];
            mr[1 * 256 + q] = A0[j].x; mr[2 * 256 + q] = A0[j].y;
            mr[3 * 256 + q] = A1[j].x; mr[4 * 256 + q] = A1[j].y;
            mr[5 * 256 + q] = A2[j].x; mr[6 * 256 + q] = A2[j].y;
            mr[7 * 256 + q] = A3[j].x; mr[8 * 256 + q] = A3[j].y;
        }
    }
    __syncthreads();
    if ((wv & 1) == 1) {
#pragma unroll
        for (int j = 0; j < 4; ++j) {
            const int q = j * 64 + lane;
            mr[q] += l[j];
            mr[1 * 256 + q] += A0[j].x; mr[2 * 256 + q] += A0[j].y;
            mr[3 * 256 + q] += A1[j].x; mr[4 * 256 + q] += A1[j].y;
            mr[5 * 256 + q] += A2[j].x; mr[6 * 256 + q] += A2[j].y;
            mr[7 * 256 + q] += A3[j].x; mr[8 * 256 + q] += A3[j].y;
        }
    }
    __syncthreads();

    // ---- single atomic layer per block (XCD-local ACC lines) ----
    const float* r0 = (const float*)lds;
    const float* r1 = (const float*)(lds + 576);
    float* ab = ACC + (size_t)wt * 2304;
    for (int idx = tid; idx < 2304; idx += 256)
        atomicAdd(ab + idx, r0[idx] + r1[idx]);
}

// ---------------------------------------------------------------------------
// normalize: read ACC, divide by l, write out[b][n][h*8+j]
// R19: 576 blocks x 64 threads for 4x scheduling units.
// ---------------------------------------------------------------------------
__global__ __launch_bounds__(64) void norm_kernel(const float* __restrict__ ACC,
                                                  float* __restrict__ out) {
    const int bxx = blockIdx.x;
    const int wt = bxx >> 2;
    const int q = (bxx & 3) * 64 + threadIdx.x;
    const float* ab = ACC + (size_t)wt * 2304;
    const float inv = 1.0f / ab[q];
    float s[8];
#pragma unroll
    for (int e = 0; e < 8; ++e) s[e] = ab[(1 + e) * 256 + q] * inv;
    const int bh = wt / 9;
    const int qtl = wt - bh * 9;
    const int n = qtl * 256 + q;
    const int b = bh >> 3, h = bh & 7;
    float* op = out + ((size_t)(b * NQ + n) * 64 + h * 8);
    ((float4*)op)[0] = make_float4(s[0], s[1], s[2], s[3]);
    ((float4*)op)[1] = make_float4(s[4], s[5], s[6], s[7]);
}

extern "C" void kernel_launch(void* const* d_in, const int* in_sizes, int n_in,
                              void* d_out, int out_size, void* d_ws, size_t ws_size,
                              hipStream_t stream) {
    const float* in   = (const float*)d_in[0];
    const float* relw = (const float*)d_in[1];
    const float* relh = (const float*)d_in[2];
    float* ACC = (float*)d_ws;                 // 1.33 MB
    float* out = (float*)d_out;

    hipMemsetAsync(ACC, 0, ACCF * sizeof(float), stream);
    attn_kernel<<<16 * NWT, 256, 0, stream>>>(in, relw, relh, ACC);
    norm_kernel<<<4 * NWT, 64, 0, stream>>>(ACC, out);
}

// Round 5
// 116.249 us; speedup vs baseline: 1.7203x; 1.0194x over previous
//
#include <hip/hip_runtime.h>
#include <stdint.h>

#define WW 48
#define NQ 2304             // 48*48
#define NWT 144             // (bh, qt) tiles of 256 queries
#define SCL 0.51011868f     // 8^-0.5 * log2(e)  (folded so softmax = exp2)
#define SHIFT 17.312340491f // 12 * log2(e)      (fixed-shift softmax)
#define ACCF (NWT * 2304)   // 331776 floats: ACC[wt][9][256]
// ws layout (floats): [0,ACCF) ACC   (QH stage eliminated in R22)

typedef float v2f __attribute__((ext_vector_type(2)));

__device__ __forceinline__ v2f v2fma(v2f a, v2f b, v2f c) {
    return __builtin_elementwise_fma(a, b, c);   // -> v_pk_fma_f32
}

// ---------------------------------------------------------------------------
// attn: R24 = R23 body with per-lane q-ownership halved (j: 4 -> 2) to cut
// VGPR below the 64-register / 8-waves-per-SIMD occupancy cliff.
// R23 counters (67.1us): SGPR 112 (s_load promotion fired), VALUBusy 64%
// (quad-pump-scaled => real issue ~21us of 67), Occ 28% -> stall-bound with
// TLP capped at 4 waves/SIMD by VGPR=84. R20: in-wave ILP unaffordable
// (VGPR spill). R21: more blocks at same waves/SIMD cap = no gain. R24
// raises the cap: each block covers 128 queries (sub = half-tile), grid
// 2304 -> 4608; array state 92 -> ~46 VGPR; __launch_bounds__(256,4)
// (empirically forces 64 VGPR on this toolchain — R11; spilled for the j=4
// body, fits the j=2 body). Total VALU/s_load/qh/atomic work invariant
// (waves x2, j /2); per-block overhead (relh stage, merge) doubles — small.
// LDS 18.4 -> 9.2KB. XCD affinity kept: bx = gs*144+wt, 144%8==0.
// Diagnostic: VGPR ~60-64 + WRITE_SIZE flat 20.7MB = healthy; WRITE
// inflation = spill = revert.
// logit = q.k + q.rel_w[x2-x+47] + q.rel_h[y2-y+47]; p = exp2(logit-SHIFT)
// ---------------------------------------------------------------------------
__global__ __launch_bounds__(256, 4) void attn_kernel(const float* __restrict__ in,
                                                      const float* __restrict__ relw,
                                                      const float* __restrict__ relh,
                                                      float* __restrict__ ACC) {
    __shared__ float4 lds[576];        // 9216 B: [0,190) relh during loop;
                                       // [0,576) 2 merge regions after loop

    const int bx = blockIdx.x;
    const int wt = bx % NWT;           // same-wt blocks share bx%8 -> same XCD
    const int gs = bx / NWT;           // 0..31 = gg*2 + sub
    const int gg = gs >> 1;            // 0..15 (one 3-column chunk each)
    const int sub = gs & 1;            // 0..1  (which 128-query half-tile)
    const int bh = wt / 9;
    const int qt = wt - bh * 9;
    const int tid = threadIdx.x;
    const int lane = tid & 63;
    const int wv = tid >> 6;           // 0..3 = row quarter (divergent form)
    const int wvu = __builtin_amdgcn_readfirstlane(wv);  // provably uniform
    const int kc = gg;                 // chunk column group (3 columns)
    const int b = bh >> 3, h = bh & 7;

    // ---- stage relh: 95 rows x 8 floats = 190 float4 ----
    for (int t = tid; t < 190; t += 256) lds[t] = ((const float4*)relh)[t];

    // ---- this lane's two queries (packed fp32 pairs) ----
    v2f Q0[2], Q1[2], Q2[2], Q3[2];
    int xq[2], ro[2];
#pragma unroll
    for (int j = 0; j < 2; ++j) {
        const int n = qt * 256 + sub * 128 + j * 64 + lane;
        const int y = n / WW;
        xq[j] = n - y * WW;
        ro[j] = (47 - y) * 8;          // relh row offset (floats), + y2*8 in loop
        const float* qp = in + ((size_t)(b * NQ + n) * 192 + h * 8);
        float4 a = *(const float4*)qp, bb = *(const float4*)(qp + 4);
        Q0[j] = (v2f){a.x * SCL, a.y * SCL};
        Q1[j] = (v2f){a.z * SCL, a.w * SCL};
        Q2[j] = (v2f){bb.x * SCL, bb.y * SCL};
        Q3[j] = (v2f){bb.z * SCL, bb.w * SCL};
    }

    // ---- qw per (query, chunk column) from global relw; SHIFT folded in ----
    float qw[2][3];
#pragma unroll
    for (int j = 0; j < 2; ++j)
#pragma unroll
        for (int c = 0; c < 3; ++c) {
            const float* rw = relw + (kc * 3 + c - xq[j] + 47) * 8;
            float4 ta = *(const float4*)rw, tb = *(const float4*)(rw + 4);
            v2f s = v2fma(Q0[j], (v2f){ta.x, ta.y},
                    v2fma(Q1[j], (v2f){ta.z, ta.w},
                    v2fma(Q2[j], (v2f){tb.x, tb.y},
                          Q3[j] * (v2f){tb.z, tb.w})));
            qw[j][c] = s.x + s.y - SHIFT;
        }

    __syncthreads();   // staged relh visible to all 4 waves

    float l[2] = {0, 0};
    v2f A0[2], A1[2], A2[2], A3[2];
#pragma unroll
    for (int j = 0; j < 2; ++j) {
        A0[j] = (v2f){0.f, 0.f}; A1[j] = (v2f){0.f, 0.f};
        A2[j] = (v2f){0.f, 0.f}; A3[j] = (v2f){0.f, 0.f};
    }
    const float* relh_lds = (const float*)lds;

#pragma unroll 1
    for (int R = 0; R < 3; ++R) {
#pragma unroll 2
        for (int row = 0; row < 4; ++row) {
            const int y2 = wvu * 12 + R * 4 + row;      // uniform chain
            // ---- qh inline: 2 near-broadcast LDS reads + 4 pk_fma per j ----
            float qhv[2];
#pragma unroll
            for (int j = 0; j < 2; ++j) {
                const float* rp = relh_lds + ro[j] + y2 * 8;
                const float4 ra = *(const float4*)rp;
                const float4 rb = *(const float4*)(rp + 4);
                v2f s = v2fma(Q0[j], (v2f){ra.x, ra.y},
                        v2fma(Q1[j], (v2f){ra.z, ra.w},
                        v2fma(Q2[j], (v2f){rb.x, rb.y},
                              Q3[j] * (v2f){rb.z, rb.w})));
                qhv[j] = s.x + s.y;
            }
            // ---- K/V: wave-uniform 32B chunks straight from global ----
            const float* kvrow = in + (size_t)(b * NQ + y2 * 48 + kc * 3) * 192
                                    + h * 8;
#pragma unroll
            for (int c = 0; c < 3; ++c) {
                const float* kvb = kvrow + c * 192;
                const float4 k0 = *(const float4*)(kvb + 64);
                const float4 k1 = *(const float4*)(kvb + 68);
                const float4 v0 = *(const float4*)(kvb + 128);
                const float4 v1 = *(const float4*)(kvb + 132);
                const v2f K0 = {k0.x, k0.y}, K1 = {k0.z, k0.w};
                const v2f K2 = {k1.x, k1.y}, K3 = {k1.z, k1.w};
                const v2f V0 = {v0.x, v0.y}, V1 = {v0.z, v0.w};
                const v2f V2 = {v1.x, v1.y}, V3 = {v1.z, v1.w};
#pragma unroll
                for (int j = 0; j < 2; ++j) {
                    v2f d = v2fma(Q0[j], K0,
                            v2fma(Q1[j], K1,
                            v2fma(Q2[j], K2, Q3[j] * K3)));
                    const float p = __builtin_amdgcn_exp2f(
                        (qhv[j] + qw[j][c]) + (d.x + d.y));
                    l[j] += p;
                    const v2f pp = {p, p};
                    A0[j] = v2fma(pp, V0, A0[j]);
                    A1[j] = v2fma(pp, V1, A1[j]);
                    A2[j] = v2fma(pp, V2, A2[j]);
                    A3[j] = v2fma(pp, V3, A3[j]);
                }
            }
        }
    }

    // ---- two-phase in-block merge (LDS: 2 regions of 1152 floats) ----
    // region layout: [e][128], e=0 -> l, e=1..8 -> A components
    __syncthreads();   // all waves done reading relh; safe to overwrite
    float* mr = (float*)(lds + (wv >> 1) * 288);   // region per wave-pair
    if ((wv & 1) == 0) {
#pragma unroll
        for (int j = 0; j < 2; ++j) {
            const int q = j * 64 + lane;
            mr[q] = l[j];
            mr[1 * 128 + q] = A0[j].x; mr[2 * 128 + q] = A0[j].y;
            mr[3 * 128 + q] = A1[j].x; mr[4 * 128 + q] = A1[j].y;
            mr[5 * 128 + q] = A2[j].x; mr[6 * 128 + q] = A2[j].y;
            mr[7 * 128 + q] = A3[j].x; mr[8 * 128 + q] = A3[j].y;
        }
    }
    __syncthreads();
    if ((wv & 1) == 1) {
#pragma unroll
        for (int j = 0; j < 2; ++j) {
            const int q = j * 64 + lane;
            mr[q] += l[j];
            mr[1 * 128 + q] += A0[j].x; mr[2 * 128 + q] += A0[j].y;
            mr[3 * 128 + q] += A1[j].x; mr[4 * 128 + q] += A1[j].y;
            mr[5 * 128 + q] += A2[j].x; mr[6 * 128 + q] += A2[j].y;
            mr[7 * 128 + q] += A3[j].x; mr[8 * 128 + q] += A3[j].y;
        }
    }
    __syncthreads();

    // ---- single atomic layer per block (XCD-local ACC lines) ----
    const float* r0 = (const float*)lds;
    const float* r1 = (const float*)(lds + 288);
    float* ab = ACC + (size_t)wt * 2304 + sub * 128;
    for (int idx = tid; idx < 1152; idx += 256) {
        const int e = idx >> 7, qq = idx & 127;
        atomicAdd(ab + e * 256 + qq, r0[idx] + r1[idx]);
    }
}

// ---------------------------------------------------------------------------
// normalize: read ACC, divide by l, write out[b][n][h*8+j]
// R19: 576 blocks x 64 threads for 4x scheduling units.
// ---------------------------------------------------------------------------
__global__ __launch_bounds__(64) void norm_kernel(const float* __restrict__ ACC,
                                                  float* __restrict__ out) {
    const int bxx = blockIdx.x;
    const int wt = bxx >> 2;
    const int q = (bxx & 3) * 64 + threadIdx.x;
    const float* ab = ACC + (size_t)wt * 2304;
    const float inv = 1.0f / ab[q];
    float s[8];
#pragma unroll
    for (int e = 0; e < 8; ++e) s[e] = ab[(1 + e) * 256 + q] * inv;
    const int bh = wt / 9;
    const int qtl = wt - bh * 9;
    const int n = qtl * 256 + q;
    const int b = bh >> 3, h = bh & 7;
    float* op = out + ((size_t)(b * NQ + n) * 64 + h * 8);
    ((float4*)op)[0] = make_float4(s[0], s[1], s[2], s[3]);
    ((float4*)op)[1] = make_float4(s[4], s[5], s[6], s[7]);
}

extern "C" void kernel_launch(void* const* d_in, const int* in_sizes, int n_in,
                              void* d_out, int out_size, void* d_ws, size_t ws_size,
                              hipStream_t stream) {
    const float* in   = (const float*)d_in[0];
    const float* relw = (const float*)d_in[1];
    const float* relh = (const float*)d_in[2];
    float* ACC = (float*)d_ws;                 // 1.33 MB
    float* out = (float*)d_out;

    hipMemsetAsync(ACC, 0, ACCF * sizeof(float), stream);
    attn_kernel<<<32 * NWT, 256, 0, stream>>>(in, relw, relh, ACC);
    norm_kernel<<<4 * NWT, 64, 0, stream>>>(ACC, out);
}

// Round 8
// 109.461 us; speedup vs baseline: 1.8270x; 1.0620x over previous
//
#include <hip/hip_runtime.h>
#include <stdint.h>

#define WW 48
#define NQ 2304             // 48*48
#define NWT 144             // (bh, qt) tiles of 256 queries
#define SCL 0.51011868f     // 8^-0.5 * log2(e)  (folded so softmax = exp2)
#define SHIFT 17.312340491f // 12 * log2(e)      (fixed-shift softmax)
#define ACCF (NWT * 2304)   // 331776 floats: ACC[wt][9][256]
// ws layout (floats): [0,ACCF) ACC

typedef float v2f __attribute__((ext_vector_type(2)));

__device__ __forceinline__ v2f v2fma(v2f a, v2f b, v2f c) {
    return __builtin_elementwise_fma(a, b, c);   // -> v_pk_fma_f32
}

// ---------------------------------------------------------------------------
// attn: R27 = R26 RESUBMITTED UNCHANGED (R26 bench was an infrastructure
// failure — "container failed twice" — no counters; theory still untested).
// R26 = R24 body (last PASSING version) + t2 fma-init fold + XCD-keyed
// grid permutation for K/V L2 locality. Fusion of norm REVERTED: R25 failed
// correctness (absmax 2.69) — cross-block ACC consume inside one launch is
// not coherent with plain loads (G16); the separate-dispatch boundary
// provides the coherence. Non-attn time is ~50us FIXED harness overhead
// (constant across R19-R24 even when whole kernels were deleted) — attn is
// the only real dial.
// R23/R24 evidence: FETCH 20.8MB vs 3.4MB input = 6x amplification. Blocks
// sharing a K/V chunk (key=(bh,gg)) had qt in bx%8 -> sharers spread over
// all 8 XCDs -> every XCD L2 refetches K/V from HBM; main-loop s_loads eat
// ~900cy HBM-miss latency in the lgkmcnt dependency path (the stall floor
// that kept VALUBusy ~65% across occ 17->47%).
// R26: bx%8 = h. ALL blocks touching head h (Q,K,V slices + ACC slabs) run
// on one XCD; per-XCD working set ~600KB << 4MB L2. Pure index permutation.
// bx = ((((gg*2+sub)*9 + qt)*2 + b) << 3) | h
// __launch_bounds__(256,4): R24 measured VGPR 44, no spill, occ 47%.
// R20/R21 lessons: no in-register K/V pipelining (spills); more blocks at
// the same waves/SIMD cap = no gain. R25 lesson: no in-launch finish
// counters without agent-scope loads.
// logit = q.k + q.rel_w[x2-x+47] + q.rel_h[y2-y+47]; p = exp2(logit-SHIFT)
// ---------------------------------------------------------------------------
__global__ __launch_bounds__(256, 4) void attn_kernel(const float* __restrict__ in,
                                                      const float* __restrict__ relw,
                                                      const float* __restrict__ relh,
                                                      float* __restrict__ ACC) {
    __shared__ float4 lds[576];        // 9216 B: [0,190) relh during loop;
                                       // [0,576) 2 merge regions after loop

    const int bx = blockIdx.x;
    // ---- XCD-keyed decode: bx%8 = h ----
    const int h = bx & 7;
    const int rest = bx >> 3;          // 0..575
    const int b = rest & 1;
    const int qg = rest >> 1;          // 0..287 = gs*9 + qt
    const int qt = qg % 9;
    const int gs = qg / 9;             // 0..31 = gg*2 + sub
    const int gg = gs >> 1;            // 0..15 (one 3-column chunk each)
    const int sub = gs & 1;            // 0..1  (which 128-query half-tile)
    const int bh = b * 8 + h;
    const int wt = bh * 9 + qt;
    const int tid = threadIdx.x;
    const int lane = tid & 63;
    const int wv = tid >> 6;           // 0..3 = row quarter (divergent form)
    const int wvu = __builtin_amdgcn_readfirstlane(wv);  // provably uniform
    const int kc = gg;                 // chunk column group (3 columns)

    // ---- stage relh: 95 rows x 8 floats = 190 float4 ----
    for (int t = tid; t < 190; t += 256) lds[t] = ((const float4*)relh)[t];

    // ---- this lane's two queries (packed fp32 pairs) ----
    v2f Q0[2], Q1[2], Q2[2], Q3[2];
    int xq[2], ro[2];
#pragma unroll
    for (int j = 0; j < 2; ++j) {
        const int n = qt * 256 + sub * 128 + j * 64 + lane;
        const int y = n / WW;
        xq[j] = n - y * WW;
        ro[j] = (47 - y) * 8;          // relh row offset (floats), + y2*8 in loop
        const float* qp = in + ((size_t)(b * NQ + n) * 192 + h * 8);
        float4 a = *(const float4*)qp, bb = *(const float4*)(qp + 4);
        Q0[j] = (v2f){a.x * SCL, a.y * SCL};
        Q1[j] = (v2f){a.z * SCL, a.w * SCL};
        Q2[j] = (v2f){bb.x * SCL, bb.y * SCL};
        Q3[j] = (v2f){bb.z * SCL, bb.w * SCL};
    }

    // ---- qw per (query, chunk column) from global relw; SHIFT folded in ----
    float qw[2][3];
#pragma unroll
    for (int j = 0; j < 2; ++j)
#pragma unroll
        for (int c = 0; c < 3; ++c) {
            const float* rw = relw + (kc * 3 + c - xq[j] + 47) * 8;
            float4 ta = *(const float4*)rw, tb = *(const float4*)(rw + 4);
            v2f s = v2fma(Q0[j], (v2f){ta.x, ta.y},
                    v2fma(Q1[j], (v2f){ta.z, ta.w},
                    v2fma(Q2[j], (v2f){tb.x, tb.y},
                          Q3[j] * (v2f){tb.z, tb.w})));
            qw[j][c] = s.x + s.y - SHIFT;
        }

    __syncthreads();   // staged relh visible to all 4 waves

    float l[2] = {0, 0};
    v2f A0[2], A1[2], A2[2], A3[2];
#pragma unroll
    for (int j = 0; j < 2; ++j) {
        A0[j] = (v2f){0.f, 0.f}; A1[j] = (v2f){0.f, 0.f};
        A2[j] = (v2f){0.f, 0.f}; A3[j] = (v2f){0.f, 0.f};
    }
    const float* relh_lds = (const float*)lds;

#pragma unroll 1
    for (int R = 0; R < 3; ++R) {
#pragma unroll 2
        for (int row = 0; row < 4; ++row) {
            const int y2 = wvu * 12 + R * 4 + row;      // uniform chain
            // ---- qh inline: 2 near-broadcast LDS reads + 4 pk_fma per j ----
            float qhv[2];
#pragma unroll
            for (int j = 0; j < 2; ++j) {
                const float* rp = relh_lds + ro[j] + y2 * 8;
                const float4 ra = *(const float4*)rp;
                const float4 rb = *(const float4*)(rp + 4);
                v2f s = v2fma(Q0[j], (v2f){ra.x, ra.y},
                        v2fma(Q1[j], (v2f){ra.z, ra.w},
                        v2fma(Q2[j], (v2f){rb.x, rb.y},
                              Q3[j] * (v2f){rb.z, rb.w})));
                qhv[j] = s.x + s.y;
            }
            // ---- t2 = qh + qw per (j,c): becomes the fma-chain init ----
            float t2[2][3];
#pragma unroll
            for (int j = 0; j < 2; ++j)
#pragma unroll
                for (int c = 0; c < 3; ++c) t2[j][c] = qhv[j] + qw[j][c];
            // ---- K/V: wave-uniform 32B chunks straight from global ----
            const float* kvrow = in + (size_t)(b * NQ + y2 * 48 + kc * 3) * 192
                                    + h * 8;
#pragma unroll
            for (int c = 0; c < 3; ++c) {
                const float* kvb = kvrow + c * 192;
                const float4 k0 = *(const float4*)(kvb + 64);
                const float4 k1 = *(const float4*)(kvb + 68);
                const float4 v0 = *(const float4*)(kvb + 128);
                const float4 v1 = *(const float4*)(kvb + 132);
                const v2f K0 = {k0.x, k0.y}, K1 = {k0.z, k0.w};
                const v2f K2 = {k1.x, k1.y}, K3 = {k1.z, k1.w};
                const v2f V0 = {v0.x, v0.y}, V1 = {v0.z, v0.w};
                const v2f V2 = {v1.x, v1.y}, V3 = {v1.z, v1.w};
#pragma unroll
                for (int j = 0; j < 2; ++j) {
                    v2f d = v2fma(Q0[j], K0,
                            v2fma(Q1[j], K1,
                            v2fma(Q2[j], K2,
                            v2fma(Q3[j], K3, (v2f){t2[j][c], 0.f}))));
                    const float p = __builtin_amdgcn_exp2f(d.x + d.y);
                    l[j] += p;
                    const v2f pp = {p, p};
                    A0[j] = v2fma(pp, V0, A0[j]);
                    A1[j] = v2fma(pp, V1, A1[j]);
                    A2[j] = v2fma(pp, V2, A2[j]);
                    A3[j] = v2fma(pp, V3, A3[j]);
                }
            }
        }
    }

    // ---- two-phase in-block merge (LDS: 2 regions of 1152 floats) ----
    // region layout: [e][128], e=0 -> l, e=1..8 -> A components
    __syncthreads();   // all waves done reading relh; safe to overwrite
    float* mr = (float*)(lds + (wv >> 1) * 288);   // region per wave-pair
    if ((wv & 1) == 0) {
#pragma unroll
        for (int j = 0; j < 2; ++j) {
            const int q = j * 64 + lane;
            mr[q] = l[j];
            mr[1 * 128 + q] = A0[j].x; mr[2 * 128 + q] = A0[j].y;
            mr[3 * 128 + q] = A1[j].x; mr[4 * 128 + q] = A1[j].y;
            mr[5 * 128 + q] = A2[j].x; mr[6 * 128 + q] = A2[j].y;
            mr[7 * 128 + q] = A3[j].x; mr[8 * 128 + q] = A3[j].y;
        }
    }
    __syncthreads();
    if ((wv & 1) == 1) {
#pragma unroll
        for (int j = 0; j < 2; ++j) {
            const int q = j * 64 + lane;
            mr[q] += l[j];
            mr[1 * 128 + q] += A0[j].x; mr[2 * 128 + q] += A0[j].y;
            mr[3 * 128 + q] += A1[j].x; mr[4 * 128 + q] += A1[j].y;
            mr[5 * 128 + q] += A2[j].x; mr[6 * 128 + q] += A2[j].y;
            mr[7 * 128 + q] += A3[j].x; mr[8 * 128 + q] += A3[j].y;
        }
    }
    __syncthreads();

    // ---- single atomic layer per block (XCD-local ACC lines) ----
    const float* r0 = (const float*)lds;
    const float* r1 = (const float*)(lds + 288);
    float* ab = ACC + (size_t)wt * 2304 + sub * 128;
    for (int idx = tid; idx < 1152; idx += 256) {
        const int e = idx >> 7, qq = idx & 127;
        atomicAdd(ab + e * 256 + qq, r0[idx] + r1[idx]);
    }
}

// ---------------------------------------------------------------------------
// normalize: read ACC, divide by l, write out[b][n][h*8+j]
// Separate dispatch (R25 lesson: the kernel boundary IS the coherence
// mechanism for the cross-block ACC consume).
// ---------------------------------------------------------------------------
__global__ __launch_bounds__(64) void norm_kernel(const float* __restrict__ ACC,
                                                  float* __restrict__ out) {
    const int bxx = blockIdx.x;
    const int wt = bxx >> 2;
    const int q = (bxx & 3) * 64 + threadIdx.x;
    const float* ab = ACC + (size_t)wt * 2304;
    const float inv = 1.0f / ab[q];
    float s[8];
#pragma unroll
    for (int e = 0; e < 8; ++e) s[e] = ab[(1 + e) * 256 + q] * inv;
    const int bh = wt / 9;
    const int qtl = wt - bh * 9;
    const int n = qtl * 256 + q;
    const int b = bh >> 3, h = bh & 7;
    float* op = out + ((size_t)(b * NQ + n) * 64 + h * 8);
    ((float4*)op)[0] = make_float4(s[0], s[1], s[2], s[3]);
    ((float4*)op)[1] = make_float4(s[4], s[5], s[6], s[7]);
}

extern "C" void kernel_launch(void* const* d_in, const int* in_sizes, int n_in,
                              void* d_out, int out_size, void* d_ws, size_t ws_size,
                              hipStream_t stream) {
    const float* in   = (const float*)d_in[0];
    const float* relw = (const float*)d_in[1];
    const float* relh = (const float*)d_in[2];
    float* ACC = (float*)d_ws;                 // 1.33 MB
    float* out = (float*)d_out;

    hipMemsetAsync(ACC, 0, ACCF * sizeof(float), stream);
    attn_kernel<<<32 * NWT, 256, 0, stream>>>(in, relw, relh, ACC);
    norm_kernel<<<4 * NWT, 64, 0, stream>>>(ACC, out);
}